// Round 2
// baseline (1102.161 us; speedup 1.0000x reference)
//
#include <hip/hip_runtime.h>

// GraphSAGE 3-layer forward on MI355X.
// Strategy: build CSR (dst-grouped incoming edges) once per call, then per layer:
//   aggregate: h_neigh[v] = mean_{u in N_in(v)} h[u]   (pure gather, no atomics)
//   gemm:      out = h @ W_self + h_neigh @ W_neigh + b (+ReLU)   fused as
//              [h, h_neigh](N x 256) @ [Ws; Wn](256 x Fo)

#define F_IN 128

__global__ __launch_bounds__(256) void count_deg_kernel(
    const int* __restrict__ dst, int* __restrict__ cnt, int E) {
    int i = blockIdx.x * 256 + threadIdx.x;
    if (i < E) atomicAdd(&cnt[dst[i]], 1);
}

__global__ __launch_bounds__(1024) void scan_kernel(
    const int* __restrict__ cnt, int* __restrict__ row_ptr, int n) {
    __shared__ int partial[1024];
    int t = threadIdx.x;
    int CH = (n + 1023) >> 10;           // chunk per thread
    int base = t * CH;
    int s = 0;
    for (int i = 0; i < CH; ++i) {
        int idx = base + i;
        if (idx < n) s += cnt[idx];
    }
    partial[t] = s;
    __syncthreads();
    // Hillis-Steele inclusive scan over 1024 partials (double-read-then-barrier)
    for (int off = 1; off < 1024; off <<= 1) {
        int v = partial[t];
        int add = (t >= off) ? partial[t - off] : 0;
        __syncthreads();
        partial[t] = v + add;
        __syncthreads();
    }
    int run = (t == 0) ? 0 : partial[t - 1];   // exclusive prefix of my chunk
    for (int i = 0; i < CH; ++i) {
        int idx = base + i;
        if (idx < n) { row_ptr[idx] = run; run += cnt[idx]; }
    }
    if (t == 1023) row_ptr[n] = run;           // == E (trailing chunks are empty)
}

__global__ __launch_bounds__(256) void fill_kernel(
    const int* __restrict__ src, const int* __restrict__ dst,
    const int* __restrict__ row_ptr, int* __restrict__ cursor,
    int* __restrict__ col, int E) {
    int i = blockIdx.x * 256 + threadIdx.x;
    if (i < E) {
        int d = dst[i];
        int pos = atomicAdd(&cursor[d], 1);
        col[row_ptr[d] + pos] = src[i];
    }
}

// One 32-lane group per node; each lane owns a float4 (4 feats) of the 128-feat row.
// 4-way unrolled: 4 independent 16B gathers in flight per lane.
__global__ __launch_bounds__(256) void aggregate_kernel(
    const float* __restrict__ h, const int* __restrict__ row_ptr,
    const int* __restrict__ col, float* __restrict__ hn, int n) {
    int g = (blockIdx.x * 256 + threadIdx.x) >> 5;   // node id
    int lane = threadIdx.x & 31;
    if (g >= n) return;
    int s = row_ptr[g], e = row_ptr[g + 1];
    const float4* h4 = (const float4*)h;
    float4 acc = make_float4(0.f, 0.f, 0.f, 0.f);
    int i = s;
    for (; i + 3 < e; i += 4) {
        int u0 = col[i], u1 = col[i + 1], u2 = col[i + 2], u3 = col[i + 3];
        float4 x0 = h4[(size_t)u0 * 32 + lane];
        float4 x1 = h4[(size_t)u1 * 32 + lane];
        float4 x2 = h4[(size_t)u2 * 32 + lane];
        float4 x3 = h4[(size_t)u3 * 32 + lane];
        acc.x += (x0.x + x1.x) + (x2.x + x3.x);
        acc.y += (x0.y + x1.y) + (x2.y + x3.y);
        acc.z += (x0.z + x1.z) + (x2.z + x3.z);
        acc.w += (x0.w + x1.w) + (x2.w + x3.w);
    }
    for (; i < e; ++i) {
        int u = col[i];
        float4 x = h4[(size_t)u * 32 + lane];
        acc.x += x.x; acc.y += x.y; acc.z += x.z; acc.w += x.w;
    }
    float inv = 1.f / fmaxf((float)(e - s), 1.f);
    float4 r = make_float4(acc.x * inv, acc.y * inv, acc.z * inv, acc.w * inv);
    ((float4*)hn)[(size_t)g * 32 + lane] = r;
}

// Fused GEMM: out[n x fo_real] = A(n x 128) @ Ws(128 x fo_real)
//                              + An(n x 128) @ Wn(128 x fo_real) + b  (+ReLU)
// BM = 32 rows/block. 256 threads = NTY x NTX grid; each thread: RPT rows x 4 cols.
// NTY*RPT must equal 32; NTX*4 must equal FO_PAD.
// LDS conflict audit: As compute reads = 2 distinct addrs/wave (2-way, free);
// Wt compute reads = contiguous b128 (conflict-free); staging writes contiguous.
template <int NTX, int RPT, int FO_PAD, bool RELU>
__global__ __launch_bounds__(256) void gemm_kernel(
    const float* __restrict__ A, const float* __restrict__ An,
    const float* __restrict__ Ws, const float* __restrict__ Wn,
    const float* __restrict__ b, float* __restrict__ out,
    int n, int fo_real) {
    constexpr int NTY = 256 / NTX;
    __shared__ float As[32][256];        // 32 KB: concatenated [h | h_neigh] tile
    __shared__ float Wt[32][FO_PAD];     // one 32-k slice of [Ws; Wn]

    int t = threadIdx.x;
    int block_row = blockIdx.x * 32;

    // Stage A-tile: 32 rows x 256 floats = 2048 float4s, 8 per thread.
    // flat float4 index f: row = f>>6, q = f&63 (q<32 -> A half, else An half)
    #pragma unroll
    for (int j = 0; j < 8; ++j) {
        int f = t + j * 256;
        int r = f >> 6, q = f & 63;
        int node = block_row + r;
        float4 v = make_float4(0.f, 0.f, 0.f, 0.f);
        if (node < n) {
            v = (q < 32) ? ((const float4*)A)[(size_t)node * 32 + q]
                         : ((const float4*)An)[(size_t)node * 32 + (q - 32)];
        }
        ((float4*)&As[r][0])[q] = v;
    }

    float acc[RPT][4];
    #pragma unroll
    for (int i = 0; i < RPT; ++i)
        for (int j = 0; j < 4; ++j) acc[i][j] = 0.f;

    int tx = t % NTX, ty = t / NTX;
    const int c0 = tx * 4;

    for (int kt = 0; kt < 8; ++kt) {     // 8 k-tiles of 32 over K=256
        __syncthreads();
        // Stage Wt[32][FO_PAD] from [Ws; Wn] rows kt*32..kt*32+31
        constexpr int F4 = (32 * FO_PAD / 4) / 256;   // float4s per thread
        #pragma unroll
        for (int j = 0; j < F4; ++j) {
            int f = t + j * 256;                       // float4 index
            int kk = f / (FO_PAD / 4);
            int c4 = f % (FO_PAD / 4);
            int k = kt * 32 + kk;
            const float* Wrow = (k < 128) ? &Ws[(size_t)k * fo_real]
                                          : &Wn[(size_t)(k - 128) * fo_real];
            float4 v;
            if (fo_real == FO_PAD) {
                v = ((const float4*)Wrow)[c4];
            } else {
                int c = c4 * 4;
                v.x = (c + 0 < fo_real) ? Wrow[c + 0] : 0.f;
                v.y = (c + 1 < fo_real) ? Wrow[c + 1] : 0.f;
                v.z = (c + 2 < fo_real) ? Wrow[c + 2] : 0.f;
                v.w = (c + 3 < fo_real) ? Wrow[c + 3] : 0.f;
            }
            ((float4*)&Wt[kk][0])[c4] = v;
        }
        __syncthreads();

        // Compute: k-unrolled by 4 so A reads are float4 (FMA-bound inner loop)
        #pragma unroll
        for (int kk = 0; kk < 32; kk += 4) {
            float4 a[RPT];
            #pragma unroll
            for (int i = 0; i < RPT; ++i)
                a[i] = *(const float4*)&As[ty * RPT + i][kt * 32 + kk];
            #pragma unroll
            for (int u = 0; u < 4; ++u) {
                float4 w = ((const float4*)&Wt[kk + u][0])[tx];
                #pragma unroll
                for (int i = 0; i < RPT; ++i) {
                    float av = (&a[i].x)[u];
                    acc[i][0] += av * w.x;
                    acc[i][1] += av * w.y;
                    acc[i][2] += av * w.z;
                    acc[i][3] += av * w.w;
                }
            }
        }
    }

    // Epilogue: bias (+ReLU), float4 store when the full quad is in-range.
    // c0 is 16B-aligned in the output row for both fo=128 and fo=40
    // (row stride 160B; c0*4 % 16 == 0).
    #pragma unroll
    for (int i = 0; i < RPT; ++i) {
        int node = block_row + ty * RPT + i;
        if (node >= n) continue;
        float4 v;
        v.x = acc[i][0] + b[c0 + 0 < fo_real ? c0 + 0 : 0];
        // (avoid OOB bias reads for fully-out-of-range quads below)
        if (c0 + 4 <= fo_real) {
            v.x = acc[i][0] + b[c0 + 0];
            v.y = acc[i][1] + b[c0 + 1];
            v.z = acc[i][2] + b[c0 + 2];
            v.w = acc[i][3] + b[c0 + 3];
            if (RELU) {
                v.x = fmaxf(v.x, 0.f); v.y = fmaxf(v.y, 0.f);
                v.z = fmaxf(v.z, 0.f); v.w = fmaxf(v.w, 0.f);
            }
            *(float4*)&out[(size_t)node * fo_real + c0] = v;
        } else {
            #pragma unroll
            for (int j = 0; j < 4; ++j) {
                int c = c0 + j;
                if (c < fo_real) {
                    float s = acc[i][j] + b[c];
                    if (RELU) s = fmaxf(s, 0.f);
                    out[(size_t)node * fo_real + c] = s;
                }
            }
        }
    }
}

static inline size_t align256(size_t x) { return (x + 255) & ~(size_t)255; }

extern "C" void kernel_launch(void* const* d_in, const int* in_sizes, int n_in,
                              void* d_out, int out_size, void* d_ws, size_t ws_size,
                              hipStream_t stream) {
    const float* inputs = (const float*)d_in[0];
    const int* src = (const int*)d_in[1];
    const int* dst = (const int*)d_in[2];
    const float* Ws0 = (const float*)d_in[3];
    const float* Wn0 = (const float*)d_in[4];
    const float* b0  = (const float*)d_in[5];
    const float* Ws1 = (const float*)d_in[6];
    const float* Wn1 = (const float*)d_in[7];
    const float* b1  = (const float*)d_in[8];
    const float* Ws2 = (const float*)d_in[9];
    const float* Wn2 = (const float*)d_in[10];
    const float* b2  = (const float*)d_in[11];

    const int N = in_sizes[0] / F_IN;   // 100000
    const int E = in_sizes[1];          // 1600000

    // Workspace layout (256B-aligned regions)
    char* ws = (char*)d_ws;
    size_t off = 0;
    size_t off_cnt    = off; off += align256((size_t)N * 4);
    size_t off_cursor = off; off += align256((size_t)N * 4);
    size_t zero_bytes = off;                       // cnt + cursor get memset(0)
    size_t off_rowptr = off; off += align256(((size_t)N + 1) * 4);
    size_t off_col    = off; off += align256((size_t)E * 4);
    size_t off_hneigh = off; off += align256((size_t)N * F_IN * 4);
    size_t off_bufA   = off; off += align256((size_t)N * F_IN * 4);
    size_t off_bufB   = off; off += align256((size_t)N * F_IN * 4);
    (void)ws_size;

    int*   cnt    = (int*)(ws + off_cnt);
    int*   cursor = (int*)(ws + off_cursor);
    int*   rowptr = (int*)(ws + off_rowptr);
    int*   col    = (int*)(ws + off_col);
    float* hneigh = (float*)(ws + off_hneigh);
    float* bufA   = (float*)(ws + off_bufA);
    float* bufB   = (float*)(ws + off_bufB);
    float* out    = (float*)d_out;

    hipMemsetAsync(ws, 0, zero_bytes, stream);

    int eb = (E + 255) / 256;
    count_deg_kernel<<<eb, 256, 0, stream>>>(dst, cnt, E);
    scan_kernel<<<1, 1024, 0, stream>>>(cnt, rowptr, N);
    fill_kernel<<<eb, 256, 0, stream>>>(src, dst, rowptr, cursor, col, E);

    int ab = (N * 32 + 255) / 256;      // 32 lanes per node
    int gb = (N + 31) / 32;             // 32 rows per gemm block

    // Layer 0: h0 = inputs
    aggregate_kernel<<<ab, 256, 0, stream>>>(inputs, rowptr, col, hneigh, N);
    gemm_kernel<32, 4, 128, true><<<gb, 256, 0, stream>>>(
        inputs, hneigh, Ws0, Wn0, b0, bufA, N, 128);

    // Layer 1
    aggregate_kernel<<<ab, 256, 0, stream>>>(bufA, rowptr, col, hneigh, N);
    gemm_kernel<32, 4, 128, true><<<gb, 256, 0, stream>>>(
        bufA, hneigh, Ws1, Wn1, b1, bufB, N, 128);

    // Layer 2 (40 classes, padded to 64 cols in LDS)
    aggregate_kernel<<<ab, 256, 0, stream>>>(bufB, rowptr, col, hneigh, N);
    gemm_kernel<16, 2, 64, false><<<gb, 256, 0, stream>>>(
        bufB, hneigh, Ws2, Wn2, b2, out, N, 40);
}

// Round 5
// 923.149 us; speedup vs baseline: 1.1939x; 1.1939x over previous
//
#include <hip/hip_runtime.h>

// GraphSAGE 3-layer forward on MI355X.
// Strategy: build CSR (dst-grouped incoming edges) once per call, then per layer:
//   aggregate: h_neigh[v] = mean_{u in N_in(v)} h[u]   (pure gather, no atomics)
//   gemm:      out = h @ W_self + h_neigh @ W_neigh + b (+ReLU)   fused as
//              [h, h_neigh](N x 256) @ [Ws; Wn](256 x Fo)
//
// R2 history: single-block scan_kernel was the top dispatch (191us, 0.17% occupancy).
// R3-R5: replaced with 3-dispatch parallel scan (block sums -> scan partials -> local scan).

#define F_IN 128
#define SCAN_CHUNK 1024   // counts per block in the parallel scan

__global__ __launch_bounds__(256) void count_deg_kernel(
    const int* __restrict__ dst, int* __restrict__ cnt, int E) {
    int i = blockIdx.x * 256 + threadIdx.x;
    if (i < E) atomicAdd(&cnt[dst[i]], 1);
}

// --- parallel exclusive scan of cnt[0..n) -> row_ptr[0..n], row_ptr[n]=E ---
__global__ __launch_bounds__(256) void scan_part1(
    const int* __restrict__ cnt, int* __restrict__ bsum, int n) {
    __shared__ int red[4];
    int base = blockIdx.x * SCAN_CHUNK + threadIdx.x * 4;
    int s = 0;
    if (base + 4 <= n) {
        int4 v = *(const int4*)&cnt[base];
        s = v.x + v.y + v.z + v.w;
    } else {
        for (int j = 0; j < 4; ++j) if (base + j < n) s += cnt[base + j];
    }
    for (int off = 32; off > 0; off >>= 1) s += __shfl_down(s, off, 64);
    if ((threadIdx.x & 63) == 0) red[threadIdx.x >> 6] = s;
    __syncthreads();
    if (threadIdx.x == 0)
        bsum[blockIdx.x] = red[0] + red[1] + red[2] + red[3];
}

__global__ __launch_bounds__(256) void scan_part2(int* __restrict__ bsum, int nb) {
    // single block: in-place exclusive scan of bsum[0..nb), nb <= 256
    __shared__ int tmp[256];
    int t = threadIdx.x;
    tmp[t] = (t < nb) ? bsum[t] : 0;
    __syncthreads();
    for (int off = 1; off < 256; off <<= 1) {
        int x = tmp[t];
        int add = (t >= off) ? tmp[t - off] : 0;
        __syncthreads();
        tmp[t] = x + add;
        __syncthreads();
    }
    if (t < nb) bsum[t] = (t == 0) ? 0 : tmp[t - 1];
}

__global__ __launch_bounds__(256) void scan_part3(
    const int* __restrict__ cnt, const int* __restrict__ bsum,
    int* __restrict__ row_ptr, int n, int E) {
    __shared__ int tsum[256];
    int t = threadIdx.x;
    int base = blockIdx.x * SCAN_CHUNK + t * 4;
    int c[4];
    int s = 0;
    #pragma unroll
    for (int j = 0; j < 4; ++j) {
        int idx = base + j;
        c[j] = (idx < n) ? cnt[idx] : 0;
        s += c[j];
    }
    tsum[t] = s;
    __syncthreads();
    for (int off = 1; off < 256; off <<= 1) {
        int x = tsum[t];
        int add = (t >= off) ? tsum[t - off] : 0;
        __syncthreads();
        tsum[t] = x + add;
        __syncthreads();
    }
    int p = bsum[blockIdx.x] + ((t == 0) ? 0 : tsum[t - 1]);
    #pragma unroll
    for (int j = 0; j < 4; ++j) {
        int idx = base + j;
        if (idx < n) { row_ptr[idx] = p; p += c[j]; }
    }
    if (blockIdx.x == 0 && t == 0) row_ptr[n] = E;
}

__global__ __launch_bounds__(256) void fill_kernel(
    const int* __restrict__ src, const int* __restrict__ dst,
    const int* __restrict__ row_ptr, int* __restrict__ cursor,
    int* __restrict__ col, int E) {
    int i = blockIdx.x * 256 + threadIdx.x;
    if (i < E) {
        int d = dst[i];
        int pos = atomicAdd(&cursor[d], 1);
        col[row_ptr[d] + pos] = src[i];
    }
}

// One 32-lane group per node; each lane owns a float4 (4 feats) of the 128-feat row.
// 4-way unrolled: 4 independent 16B gathers in flight per lane.
__global__ __launch_bounds__(256) void aggregate_kernel(
    const float* __restrict__ h, const int* __restrict__ row_ptr,
    const int* __restrict__ col, float* __restrict__ hn, int n) {
    int g = (blockIdx.x * 256 + threadIdx.x) >> 5;   // node id
    int lane = threadIdx.x & 31;
    if (g >= n) return;
    int s = row_ptr[g], e = row_ptr[g + 1];
    const float4* h4 = (const float4*)h;
    float4 acc = make_float4(0.f, 0.f, 0.f, 0.f);
    int i = s;
    for (; i + 3 < e; i += 4) {
        int u0 = col[i], u1 = col[i + 1], u2 = col[i + 2], u3 = col[i + 3];
        float4 x0 = h4[(size_t)u0 * 32 + lane];
        float4 x1 = h4[(size_t)u1 * 32 + lane];
        float4 x2 = h4[(size_t)u2 * 32 + lane];
        float4 x3 = h4[(size_t)u3 * 32 + lane];
        acc.x += (x0.x + x1.x) + (x2.x + x3.x);
        acc.y += (x0.y + x1.y) + (x2.y + x3.y);
        acc.z += (x0.z + x1.z) + (x2.z + x3.z);
        acc.w += (x0.w + x1.w) + (x2.w + x3.w);
    }
    for (; i < e; ++i) {
        int u = col[i];
        float4 x = h4[(size_t)u * 32 + lane];
        acc.x += x.x; acc.y += x.y; acc.z += x.z; acc.w += x.w;
    }
    float inv = 1.f / fmaxf((float)(e - s), 1.f);
    float4 r = make_float4(acc.x * inv, acc.y * inv, acc.z * inv, acc.w * inv);
    ((float4*)hn)[(size_t)g * 32 + lane] = r;
}

// Fused GEMM: out[n x fo_real] = A(n x 128) @ Ws(128 x fo_real)
//                              + An(n x 128) @ Wn(128 x fo_real) + b  (+ReLU)
// BM = 32 rows/block. 256 threads = NTY x NTX grid; each thread: RPT rows x 4 cols.
// NTY*RPT must equal 32; NTX*4 must equal FO_PAD.
// LDS conflict audit: As compute reads = 2 distinct addrs/wave (2-way, free);
// Wt compute reads = contiguous b128 (conflict-free); staging writes contiguous.
template <int NTX, int RPT, int FO_PAD, bool RELU>
__global__ __launch_bounds__(256) void gemm_kernel(
    const float* __restrict__ A, const float* __restrict__ An,
    const float* __restrict__ Ws, const float* __restrict__ Wn,
    const float* __restrict__ b, float* __restrict__ out,
    int n, int fo_real) {
    constexpr int NTY = 256 / NTX;
    __shared__ float As[32][256];        // 32 KB: concatenated [h | h_neigh] tile
    __shared__ float Wt[32][FO_PAD];     // one 32-k slice of [Ws; Wn]

    int t = threadIdx.x;
    int block_row = blockIdx.x * 32;

    // Stage A-tile: 32 rows x 256 floats = 2048 float4s, 8 per thread.
    #pragma unroll
    for (int j = 0; j < 8; ++j) {
        int f = t + j * 256;
        int r = f >> 6, q = f & 63;
        int node = block_row + r;
        float4 v = make_float4(0.f, 0.f, 0.f, 0.f);
        if (node < n) {
            v = (q < 32) ? ((const float4*)A)[(size_t)node * 32 + q]
                         : ((const float4*)An)[(size_t)node * 32 + (q - 32)];
        }
        ((float4*)&As[r][0])[q] = v;
    }

    float acc[RPT][4];
    #pragma unroll
    for (int i = 0; i < RPT; ++i)
        for (int j = 0; j < 4; ++j) acc[i][j] = 0.f;

    int tx = t % NTX, ty = t / NTX;
    const int c0 = tx * 4;

    for (int kt = 0; kt < 8; ++kt) {     // 8 k-tiles of 32 over K=256
        __syncthreads();
        // Stage Wt[32][FO_PAD] from [Ws; Wn] rows kt*32..kt*32+31
        constexpr int F4 = (32 * FO_PAD / 4) / 256;   // float4s per thread
        #pragma unroll
        for (int j = 0; j < F4; ++j) {
            int f = t + j * 256;                       // float4 index
            int kk = f / (FO_PAD / 4);
            int c4 = f % (FO_PAD / 4);
            int k = kt * 32 + kk;
            const float* Wrow = (k < 128) ? &Ws[(size_t)k * fo_real]
                                          : &Wn[(size_t)(k - 128) * fo_real];
            float4 v;
            if (fo_real == FO_PAD) {
                v = ((const float4*)Wrow)[c4];
            } else {
                int c = c4 * 4;
                v.x = (c + 0 < fo_real) ? Wrow[c + 0] : 0.f;
                v.y = (c + 1 < fo_real) ? Wrow[c + 1] : 0.f;
                v.z = (c + 2 < fo_real) ? Wrow[c + 2] : 0.f;
                v.w = (c + 3 < fo_real) ? Wrow[c + 3] : 0.f;
            }
            ((float4*)&Wt[kk][0])[c4] = v;
        }
        __syncthreads();

        // Compute: k-unrolled by 4 so A reads are float4 (FMA-bound inner loop)
        #pragma unroll
        for (int kk = 0; kk < 32; kk += 4) {
            float4 a[RPT];
            #pragma unroll
            for (int i = 0; i < RPT; ++i)
                a[i] = *(const float4*)&As[ty * RPT + i][kt * 32 + kk];
            #pragma unroll
            for (int u = 0; u < 4; ++u) {
                float4 w = ((const float4*)&Wt[kk + u][0])[tx];
                #pragma unroll
                for (int i = 0; i < RPT; ++i) {
                    float av = (&a[i].x)[u];
                    acc[i][0] += av * w.x;
                    acc[i][1] += av * w.y;
                    acc[i][2] += av * w.z;
                    acc[i][3] += av * w.w;
                }
            }
        }
    }

    // Epilogue: bias (+ReLU), float4 store when the full quad is in-range.
    // c0 is 16B-aligned in the output row for both fo=128 and fo=40
    // (row stride 160B; c0*4 % 16 == 0).
    #pragma unroll
    for (int i = 0; i < RPT; ++i) {
        int node = block_row + ty * RPT + i;
        if (node >= n) continue;
        if (c0 + 4 <= fo_real) {
            float4 v;
            v.x = acc[i][0] + b[c0 + 0];
            v.y = acc[i][1] + b[c0 + 1];
            v.z = acc[i][2] + b[c0 + 2];
            v.w = acc[i][3] + b[c0 + 3];
            if (RELU) {
                v.x = fmaxf(v.x, 0.f); v.y = fmaxf(v.y, 0.f);
                v.z = fmaxf(v.z, 0.f); v.w = fmaxf(v.w, 0.f);
            }
            *(float4*)&out[(size_t)node * fo_real + c0] = v;
        } else {
            #pragma unroll
            for (int j = 0; j < 4; ++j) {
                int c = c0 + j;
                if (c < fo_real) {
                    float s = acc[i][j] + b[c];
                    if (RELU) s = fmaxf(s, 0.f);
                    out[(size_t)node * fo_real + c] = s;
                }
            }
        }
    }
}

static inline size_t align256(size_t x) { return (x + 255) & ~(size_t)255; }

extern "C" void kernel_launch(void* const* d_in, const int* in_sizes, int n_in,
                              void* d_out, int out_size, void* d_ws, size_t ws_size,
                              hipStream_t stream) {
    const float* inputs = (const float*)d_in[0];
    const int* src = (const int*)d_in[1];
    const int* dst = (const int*)d_in[2];
    const float* Ws0 = (const float*)d_in[3];
    const float* Wn0 = (const float*)d_in[4];
    const float* b0  = (const float*)d_in[5];
    const float* Ws1 = (const float*)d_in[6];
    const float* Wn1 = (const float*)d_in[7];
    const float* b1  = (const float*)d_in[8];
    const float* Ws2 = (const float*)d_in[9];
    const float* Wn2 = (const float*)d_in[10];
    const float* b2  = (const float*)d_in[11];

    const int N = in_sizes[0] / F_IN;   // 100000
    const int E = in_sizes[1];          // 1600000

    // Workspace layout (256B-aligned regions)
    char* ws = (char*)d_ws;
    size_t off = 0;
    size_t off_cnt    = off; off += align256((size_t)N * 4);
    size_t off_cursor = off; off += align256((size_t)N * 4);
    size_t zero_bytes = off;                       // cnt + cursor get memset(0)
    size_t off_rowptr = off; off += align256(((size_t)N + 1) * 4);
    size_t off_bsum   = off; off += align256(1024 * 4);
    size_t off_col    = off; off += align256((size_t)E * 4);
    size_t off_hneigh = off; off += align256((size_t)N * F_IN * 4);
    size_t off_bufA   = off; off += align256((size_t)N * F_IN * 4);
    size_t off_bufB   = off; off += align256((size_t)N * F_IN * 4);
    (void)ws_size;

    int*   cnt    = (int*)(ws + off_cnt);
    int*   cursor = (int*)(ws + off_cursor);
    int*   rowptr = (int*)(ws + off_rowptr);
    int*   bsum   = (int*)(ws + off_bsum);
    int*   col    = (int*)(ws + off_col);
    float* hneigh = (float*)(ws + off_hneigh);
    float* bufA   = (float*)(ws + off_bufA);
    float* bufB   = (float*)(ws + off_bufB);
    float* out    = (float*)d_out;

    hipMemsetAsync(ws, 0, zero_bytes, stream);

    int eb = (E + 255) / 256;
    int nb = (N + SCAN_CHUNK - 1) / SCAN_CHUNK;    // 98 blocks (<=256 supported)

    count_deg_kernel<<<eb, 256, 0, stream>>>(dst, cnt, E);
    scan_part1<<<nb, 256, 0, stream>>>(cnt, bsum, N);
    scan_part2<<<1, 256, 0, stream>>>(bsum, nb);
    scan_part3<<<nb, 256, 0, stream>>>(cnt, bsum, rowptr, N, E);
    fill_kernel<<<eb, 256, 0, stream>>>(src, dst, rowptr, cursor, col, E);

    int ab = (N * 32 + 255) / 256;      // 32 lanes per node
    int gb = (N + 31) / 32;             // 32 rows per gemm block

    // Layer 0: h0 = inputs
    aggregate_kernel<<<ab, 256, 0, stream>>>(inputs, rowptr, col, hneigh, N);
    gemm_kernel<32, 4, 128, true><<<gb, 256, 0, stream>>>(
        inputs, hneigh, Ws0, Wn0, b0, bufA, N, 128);

    // Layer 1
    aggregate_kernel<<<ab, 256, 0, stream>>>(bufA, rowptr, col, hneigh, N);
    gemm_kernel<32, 4, 128, true><<<gb, 256, 0, stream>>>(
        bufA, hneigh, Ws1, Wn1, b1, bufB, N, 128);

    // Layer 2 (40 classes, padded to 64 cols in LDS)
    aggregate_kernel<<<ab, 256, 0, stream>>>(bufB, rowptr, col, hneigh, N);
    gemm_kernel<16, 2, 64, false><<<gb, 256, 0, stream>>>(
        bufB, hneigh, Ws2, Wn2, b2, out, N, 40);
}

// Round 10
// 909.860 us; speedup vs baseline: 1.2114x; 1.0146x over previous
//
#include <hip/hip_runtime.h>

// GraphSAGE 3-layer forward on MI355X.
// CSR build (dst-grouped) once per call, then per layer:
//   aggregate: h_neigh[v] = mean_{u in N_in(v)} h[u]   (pure gather, no atomics)
//   gemm:      out = [h | h_neigh](N x 256) @ [Ws; Wn](256 x Fo) + b (+ReLU)
//
// R2: single-block scan was top dispatch (191us, 0.17% occ).
// R5: parallel scan landed; 1102 -> 923us. gemm_kernel now top (140us/layer,
//     VALUBusy 64%, MfmaUtil 0, 47TF of 157TF f32-vector peak, occ 29% via 48KB LDS).
// R6-R10: split-bf16 MFMA GEMM (Ahi*Whi + Alo*Whi + Ahi*Wlo on 16x16x32 bf16 matrix
//     cores, f32-grade accuracy). A: global->reg (each elem used once per block,
//     no sharing -> no LDS, no barriers). W: pre-split+transposed Wt[c][k] in ws,
//     L2-hot 16B/lane loads.

#define F_IN 128
#define SCAN_CHUNK 1024

typedef __attribute__((ext_vector_type(8))) short bf16x8;
typedef __attribute__((ext_vector_type(4))) float f32x4;

__device__ __forceinline__ unsigned short f32_to_bf16_rne(float x) {
    unsigned int u = __float_as_uint(x);
    unsigned int r = u + 0x7FFFu + ((u >> 16) & 1u);   // round-to-nearest-even
    return (unsigned short)(r >> 16);
}
__device__ __forceinline__ float bf16_bits_to_f32(unsigned short h) {
    return __uint_as_float(((unsigned int)h) << 16);
}

// ---------------- CSR build ----------------

__global__ __launch_bounds__(256) void count_deg_kernel(
    const int* __restrict__ dst, int* __restrict__ cnt, int E) {
    int i = blockIdx.x * 256 + threadIdx.x;
    if (i < E) atomicAdd(&cnt[dst[i]], 1);
}

__global__ __launch_bounds__(256) void scan_part1(
    const int* __restrict__ cnt, int* __restrict__ bsum, int n) {
    __shared__ int red[4];
    int base = blockIdx.x * SCAN_CHUNK + threadIdx.x * 4;
    int s = 0;
    if (base + 4 <= n) {
        int4 v = *(const int4*)&cnt[base];
        s = v.x + v.y + v.z + v.w;
    } else {
        for (int j = 0; j < 4; ++j) if (base + j < n) s += cnt[base + j];
    }
    for (int off = 32; off > 0; off >>= 1) s += __shfl_down(s, off, 64);
    if ((threadIdx.x & 63) == 0) red[threadIdx.x >> 6] = s;
    __syncthreads();
    if (threadIdx.x == 0)
        bsum[blockIdx.x] = red[0] + red[1] + red[2] + red[3];
}

__global__ __launch_bounds__(256) void scan_part2(int* __restrict__ bsum, int nb) {
    __shared__ int tmp[256];
    int t = threadIdx.x;
    tmp[t] = (t < nb) ? bsum[t] : 0;
    __syncthreads();
    for (int off = 1; off < 256; off <<= 1) {
        int x = tmp[t];
        int add = (t >= off) ? tmp[t - off] : 0;
        __syncthreads();
        tmp[t] = x + add;
        __syncthreads();
    }
    if (t < nb) bsum[t] = (t == 0) ? 0 : tmp[t - 1];
}

__global__ __launch_bounds__(256) void scan_part3(
    const int* __restrict__ cnt, const int* __restrict__ bsum,
    int* __restrict__ row_ptr, int n, int E) {
    __shared__ int tsum[256];
    int t = threadIdx.x;
    int base = blockIdx.x * SCAN_CHUNK + t * 4;
    int c[4];
    int s = 0;
    #pragma unroll
    for (int j = 0; j < 4; ++j) {
        int idx = base + j;
        c[j] = (idx < n) ? cnt[idx] : 0;
        s += c[j];
    }
    tsum[t] = s;
    __syncthreads();
    for (int off = 1; off < 256; off <<= 1) {
        int x = tsum[t];
        int add = (t >= off) ? tsum[t - off] : 0;
        __syncthreads();
        tsum[t] = x + add;
        __syncthreads();
    }
    int p = bsum[blockIdx.x] + ((t == 0) ? 0 : tsum[t - 1]);
    #pragma unroll
    for (int j = 0; j < 4; ++j) {
        int idx = base + j;
        if (idx < n) { row_ptr[idx] = p; p += c[j]; }
    }
    if (blockIdx.x == 0 && t == 0) row_ptr[n] = E;
}

__global__ __launch_bounds__(256) void fill_kernel(
    const int* __restrict__ src, const int* __restrict__ dst,
    const int* __restrict__ row_ptr, int* __restrict__ cursor,
    int* __restrict__ col, int E) {
    int i = blockIdx.x * 256 + threadIdx.x;
    if (i < E) {
        int d = dst[i];
        int pos = atomicAdd(&cursor[d], 1);
        col[row_ptr[d] + pos] = src[i];
    }
}

// ---------------- aggregation ----------------
// One 32-lane group per node; each lane owns a float4 of the 128-feat row.
__global__ __launch_bounds__(256) void aggregate_kernel(
    const float* __restrict__ h, const int* __restrict__ row_ptr,
    const int* __restrict__ col, float* __restrict__ hn, int n) {
    int g = (blockIdx.x * 256 + threadIdx.x) >> 5;
    int lane = threadIdx.x & 31;
    if (g >= n) return;
    int s = row_ptr[g], e = row_ptr[g + 1];
    const float4* h4 = (const float4*)h;
    float4 acc = make_float4(0.f, 0.f, 0.f, 0.f);
    int i = s;
    for (; i + 3 < e; i += 4) {
        int u0 = col[i], u1 = col[i + 1], u2 = col[i + 2], u3 = col[i + 3];
        float4 x0 = h4[(size_t)u0 * 32 + lane];
        float4 x1 = h4[(size_t)u1 * 32 + lane];
        float4 x2 = h4[(size_t)u2 * 32 + lane];
        float4 x3 = h4[(size_t)u3 * 32 + lane];
        acc.x += (x0.x + x1.x) + (x2.x + x3.x);
        acc.y += (x0.y + x1.y) + (x2.y + x3.y);
        acc.z += (x0.z + x1.z) + (x2.z + x3.z);
        acc.w += (x0.w + x1.w) + (x2.w + x3.w);
    }
    for (; i < e; ++i) {
        int u = col[i];
        float4 x = h4[(size_t)u * 32 + lane];
        acc.x += x.x; acc.y += x.y; acc.z += x.z; acc.w += x.w;
    }
    float inv = 1.f / fmaxf((float)(e - s), 1.f);
    float4 r = make_float4(acc.x * inv, acc.y * inv, acc.z * inv, acc.w * inv);
    ((float4*)hn)[(size_t)g * 32 + lane] = r;
}

// ---------------- W split/transpose ----------------
// Wt_hi/Wt_lo [fopad][256] bf16; Wt[c][k] = (k<128 ? Ws[k][c] : Wn[k-128][c]),
// zero-padded for c >= fo. hi+lo split gives ~16 mantissa bits.
__global__ __launch_bounds__(256) void wsplit_kernel(
    const float* __restrict__ Ws, const float* __restrict__ Wn,
    unsigned short* __restrict__ hi, unsigned short* __restrict__ lo,
    int fo, int fopad) {
    int i = blockIdx.x * 256 + threadIdx.x;
    if (i >= fopad * 256) return;
    int c = i >> 8, k = i & 255;
    float v = 0.f;
    if (c < fo) v = (k < 128) ? Ws[(size_t)k * fo + c] : Wn[(size_t)(k - 128) * fo + c];
    unsigned short h = f32_to_bf16_rne(v);
    float hf = bf16_bits_to_f32(h);
    unsigned short l = f32_to_bf16_rne(v - hf);
    hi[i] = h; lo[i] = l;
}

// ---------------- split-bf16 MFMA GEMM ----------------
// out[n x fo] = [A | An] @ [Ws; Wn] + b (+ReLU), via 16x16x32 bf16 MFMA:
//   C = Ahi*Whi + Alo*Whi + Ahi*Wlo   (lo*lo dropped, ~2^-16 rel err)
// Block: 256 thr = 4 waves, BM=64 (16 rows/wave), NT col-tiles of 16.
// No LDS, no barriers: A global->reg+convert (each elem used once/block,
// reused across col-tiles in regs); W frags from L2-hot Wt[c][k].
// Frag layouts: A row=l&15,k=(l>>4)*8+j; B col=l&15,same k;
// C/D col=l&15,row=(l>>4)*4+reg (m89-verified).
template <int NT, bool RELU>
__global__ __launch_bounds__(256) void gemm_mfma_kernel(
    const float* __restrict__ A, const float* __restrict__ An,
    const unsigned short* __restrict__ Wt_hi,
    const unsigned short* __restrict__ Wt_lo,
    const float* __restrict__ bias, float* __restrict__ out,
    int n, int fo) {
    int wid  = threadIdx.x >> 6;
    int lane = threadIdx.x & 63;
    int r16  = lane & 15;          // A-row / B-col / C-col within tile
    int kg   = lane >> 4;          // k-group 0..3 (8 k's each)
    int Rbase = blockIdx.x * 64 + wid * 16;

    f32x4 acc[NT];
    #pragma unroll
    for (int ct = 0; ct < NT; ++ct) acc[ct] = (f32x4){0.f, 0.f, 0.f, 0.f};

    int arow = Rbase + r16;
    if (arow > n - 1) arow = n - 1;          // clamp: OOB rows discarded at store

    #pragma unroll
    for (int kstep = 0; kstep < 8; ++kstep) {
        const float* srcp = (kstep < 4) ? A : An;
        int koff = (kstep & 3) * 32 + kg * 8;              // f32 offset in [0,128)
        const float* p = srcp + (size_t)arow * F_IN + koff;
        float4 v0 = *(const float4*)p;
        float4 v1 = *(const float4*)(p + 4);

        bf16x8 ahi, alo;
        {
            float va0 = v0.x, va1 = v0.y, va2 = v0.z, va3 = v0.w;
            float va4 = v1.x, va5 = v1.y, va6 = v1.z, va7 = v1.w;
            unsigned short h0 = f32_to_bf16_rne(va0), h1 = f32_to_bf16_rne(va1);
            unsigned short h2 = f32_to_bf16_rne(va2), h3 = f32_to_bf16_rne(va3);
            unsigned short h4 = f32_to_bf16_rne(va4), h5 = f32_to_bf16_rne(va5);
            unsigned short h6 = f32_to_bf16_rne(va6), h7 = f32_to_bf16_rne(va7);
            ahi[0] = (short)h0; ahi[1] = (short)h1; ahi[2] = (short)h2; ahi[3] = (short)h3;
            ahi[4] = (short)h4; ahi[5] = (short)h5; ahi[6] = (short)h6; ahi[7] = (short)h7;
            alo[0] = (short)f32_to_bf16_rne(va0 - bf16_bits_to_f32(h0));
            alo[1] = (short)f32_to_bf16_rne(va1 - bf16_bits_to_f32(h1));
            alo[2] = (short)f32_to_bf16_rne(va2 - bf16_bits_to_f32(h2));
            alo[3] = (short)f32_to_bf16_rne(va3 - bf16_bits_to_f32(h3));
            alo[4] = (short)f32_to_bf16_rne(va4 - bf16_bits_to_f32(h4));
            alo[5] = (short)f32_to_bf16_rne(va5 - bf16_bits_to_f32(h5));
            alo[6] = (short)f32_to_bf16_rne(va6 - bf16_bits_to_f32(h6));
            alo[7] = (short)f32_to_bf16_rne(va7 - bf16_bits_to_f32(h7));
        }

        int wkoff = kstep * 32 + kg * 8;                   // bf16 k offset in [0,256)
        #pragma unroll
        for (int ct = 0; ct < NT; ++ct) {
            int c = ct * 16 + r16;
            bf16x8 whi = *(const bf16x8*)(Wt_hi + (size_t)c * 256 + wkoff);
            bf16x8 wlo = *(const bf16x8*)(Wt_lo + (size_t)c * 256 + wkoff);
            acc[ct] = __builtin_amdgcn_mfma_f32_16x16x32_bf16(ahi, whi, acc[ct], 0, 0, 0);
            acc[ct] = __builtin_amdgcn_mfma_f32_16x16x32_bf16(alo, whi, acc[ct], 0, 0, 0);
            acc[ct] = __builtin_amdgcn_mfma_f32_16x16x32_bf16(ahi, wlo, acc[ct], 0, 0, 0);
        }
    }

    // Epilogue: C/D layout col=r16, row=kg*4+i.
    #pragma unroll
    for (int ct = 0; ct < NT; ++ct) {
        int c = ct * 16 + r16;
        #pragma unroll
        for (int i = 0; i < 4; ++i) {
            int node = Rbase + kg * 4 + i;
            if (node < n && c < fo) {
                float v = acc[ct][i] + bias[c];
                if (RELU) v = fmaxf(v, 0.f);
                out[(size_t)node * fo + c] = v;
            }
        }
    }
}

static inline size_t align256(size_t x) { return (x + 255) & ~(size_t)255; }

extern "C" void kernel_launch(void* const* d_in, const int* in_sizes, int n_in,
                              void* d_out, int out_size, void* d_ws, size_t ws_size,
                              hipStream_t stream) {
    const float* inputs = (const float*)d_in[0];
    const int* src = (const int*)d_in[1];
    const int* dst = (const int*)d_in[2];
    const float* Ws0 = (const float*)d_in[3];
    const float* Wn0 = (const float*)d_in[4];
    const float* b0  = (const float*)d_in[5];
    const float* Ws1 = (const float*)d_in[6];
    const float* Wn1 = (const float*)d_in[7];
    const float* b1  = (const float*)d_in[8];
    const float* Ws2 = (const float*)d_in[9];
    const float* Wn2 = (const float*)d_in[10];
    const float* b2  = (const float*)d_in[11];

    const int N = in_sizes[0] / F_IN;   // 100000
    const int E = in_sizes[1];          // 1600000

    // Workspace layout (256B-aligned regions)
    char* ws = (char*)d_ws;
    size_t off = 0;
    size_t off_cnt    = off; off += align256((size_t)N * 4);
    size_t off_cursor = off; off += align256((size_t)N * 4);
    size_t zero_bytes = off;                       // cnt + cursor get memset(0)
    size_t off_rowptr = off; off += align256(((size_t)N + 1) * 4);
    size_t off_bsum   = off; off += align256(1024 * 4);
    size_t off_col    = off; off += align256((size_t)E * 4);
    size_t off_hneigh = off; off += align256((size_t)N * F_IN * 4);
    size_t off_bufA   = off; off += align256((size_t)N * F_IN * 4);
    size_t off_bufB   = off; off += align256((size_t)N * F_IN * 4);
    size_t off_wt0h   = off; off += align256(128 * 256 * 2);
    size_t off_wt0l   = off; off += align256(128 * 256 * 2);
    size_t off_wt1h   = off; off += align256(128 * 256 * 2);
    size_t off_wt1l   = off; off += align256(128 * 256 * 2);
    size_t off_wt2h   = off; off += align256(48 * 256 * 2);
    size_t off_wt2l   = off; off += align256(48 * 256 * 2);
    (void)ws_size;

    int*   cnt    = (int*)(ws + off_cnt);
    int*   cursor = (int*)(ws + off_cursor);
    int*   rowptr = (int*)(ws + off_rowptr);
    int*   bsum   = (int*)(ws + off_bsum);
    int*   col    = (int*)(ws + off_col);
    float* hneigh = (float*)(ws + off_hneigh);
    float* bufA   = (float*)(ws + off_bufA);
    float* bufB   = (float*)(ws + off_bufB);
    unsigned short* wt0h = (unsigned short*)(ws + off_wt0h);
    unsigned short* wt0l = (unsigned short*)(ws + off_wt0l);
    unsigned short* wt1h = (unsigned short*)(ws + off_wt1h);
    unsigned short* wt1l = (unsigned short*)(ws + off_wt1l);
    unsigned short* wt2h = (unsigned short*)(ws + off_wt2h);
    unsigned short* wt2l = (unsigned short*)(ws + off_wt2l);
    float* out    = (float*)d_out;

    hipMemsetAsync(ws, 0, zero_bytes, stream);

    int eb = (E + 255) / 256;
    int nb = (N + SCAN_CHUNK - 1) / SCAN_CHUNK;

    count_deg_kernel<<<eb, 256, 0, stream>>>(dst, cnt, E);
    scan_part1<<<nb, 256, 0, stream>>>(cnt, bsum, N);
    scan_part2<<<1, 256, 0, stream>>>(bsum, nb);
    scan_part3<<<nb, 256, 0, stream>>>(cnt, bsum, rowptr, N, E);
    fill_kernel<<<eb, 256, 0, stream>>>(src, dst, rowptr, cursor, col, E);

    // W split/transpose (tiny; independent of aggregation)
    wsplit_kernel<<<(128 * 256) / 256, 256, 0, stream>>>(Ws0, Wn0, wt0h, wt0l, 128, 128);
    wsplit_kernel<<<(128 * 256) / 256, 256, 0, stream>>>(Ws1, Wn1, wt1h, wt1l, 128, 128);
    wsplit_kernel<<<(48 * 256) / 256, 256, 0, stream>>>(Ws2, Wn2, wt2h, wt2l, 40, 48);

    int ab = (N * 32 + 255) / 256;      // aggregate: 32 lanes per node
    int gb = (N + 63) / 64;             // gemm: 64 rows per block

    // Layer 0
    aggregate_kernel<<<ab, 256, 0, stream>>>(inputs, rowptr, col, hneigh, N);
    gemm_mfma_kernel<8, true><<<gb, 256, 0, stream>>>(
        inputs, hneigh, wt0h, wt0l, b0, bufA, N, 128);

    // Layer 1
    aggregate_kernel<<<ab, 256, 0, stream>>>(bufA, rowptr, col, hneigh, N);
    gemm_mfma_kernel<8, true><<<gb, 256, 0, stream>>>(
        bufA, hneigh, wt1h, wt1l, b1, bufB, N, 128);

    // Layer 2 (40 classes, 3 col-tiles = 48 padded)
    aggregate_kernel<<<ab, 256, 0, stream>>>(bufB, rowptr, col, hneigh, N);
    gemm_mfma_kernel<3, false><<<gb, 256, 0, stream>>>(
        bufB, hneigh, wt2h, wt2l, b2, out, N, 40);
}